// Round 1
// baseline (244.966 us; speedup 1.0000x reference)
//
#include <hip/hip_runtime.h>

// Cubic B-spline prefilter (Unser), periodic boundary, along axes 2,3,4 of
// a (2,3,160,160,160) fp32 tensor. One thread per 160-element line; 64 lines
// per 64-thread block staged in LDS (exactly 40 KB -> 4 blocks/CU).
//
// LDS layout: line l element n at lds[l*160 + (n ^ (l&31))].
//   - 160 = 5*32, so n ^ (l&31) is closed within each 32-aligned block of n
//     (valid permutation of 0..159 per line, no padding needed).
//   - bank = (n ^ (l&31)) & 31: at fixed n across 64 lanes -> every bank hit
//     by exactly 2 lanes (free).  Naive [64][160] would be 64-way conflicted
//     (160 % 32 == 0).

#define NLINE 160
#define LPB   64   // lines (== threads) per block

__device__ __forceinline__ int swz(int l, int n) {
    return l * NLINE + (n ^ (l & 31));
}

template <int I>  // stride between successive elements of a line; I==1 => lines contiguous
__global__ __launch_bounds__(LPB)
void prefilter(const float* __restrict__ in, float* __restrict__ out)
{
    __shared__ float lds[LPB * NLINE];   // 40 KB
    const int tid = threadIdx.x;
    const int L0  = blockIdx.x * LPB;    // first line of this block

    // ---- load 64 lines into LDS (coalesced) ----
    if (I == 1) {
        // lines contiguous: block covers a contiguous 40 KB chunk
        const float* src = in + (size_t)L0 * NLINE;
        #pragma unroll 4
        for (int idx = tid; idx < LPB * NLINE; idx += LPB) {
            const int l = idx / NLINE;
            const int n = idx - l * NLINE;
            lds[swz(l, n)] = src[idx];
        }
    } else {
        const int L = L0 + tid;
        const int o = L / I;
        const int i = L - o * I;
        const float* src = in + (size_t)o * NLINE * I + i;
        #pragma unroll 4
        for (int n = 0; n < NLINE; ++n)
            lds[swz(tid, n)] = src[(size_t)n * I];
    }
    __syncthreads();

    // ---- per-thread IIR on line `tid`, entirely in LDS ----
    {
        const float z = -0.26794919243112270647f;  // sqrt(3) - 2
        float* line = lds + tid * NLINE;
        const int xo = tid & 31;

        // causal init (periodic): acc = sum_{idx=1..N-1} z^(N-idx) * x[idx]
        // (z^160 underflows to 0 in fp32, so the 1/(1-z^N) factor is exactly 1,
        //  matching the fp32 JAX reference.)
        float acc = line[1 ^ xo];
        #pragma unroll 8
        for (int idx = 2; idx < NLINE; ++idx)
            acc = fmaf(acc, z, line[idx ^ xo]);
        acc *= z;

        // forward sweep: cp[n] = 6*x[n] + z*cp[n-1]
        // simultaneously accumulate T = sum_{k=1..N-1} z^k * cp[k-1]
        float cp = 6.0f * (line[0 ^ xo] + acc);
        line[0 ^ xo] = cp;
        float T = 0.0f, zp = z;
        #pragma unroll 8
        for (int n = 1; n < NLINE; ++n) {
            const float cn = fmaf(z, cp, 6.0f * line[n ^ xo]);
            T  = fmaf(zp, cp, T);      // adds z^n * cp[n-1]
            zp *= z;
            cp = cn;
            line[n ^ xo] = cp;
        }

        // anticausal init: cm[N-1] = -z * ( cp[N-1] + sum_{k=1..N-1} z^k cp[k-1] )
        float cm = -z * (cp + T);
        line[(NLINE - 1) ^ xo] = cm;

        // backward sweep: cm[n] = z * (cm[n+1] - cp[n])
        #pragma unroll 8
        for (int n = NLINE - 2; n >= 0; --n) {
            cm = z * (cm - line[n ^ xo]);
            line[n ^ xo] = cm;
        }
    }
    __syncthreads();

    // ---- store 64 lines back (coalesced) ----
    if (I == 1) {
        float* dst = out + (size_t)L0 * NLINE;
        #pragma unroll 4
        for (int idx = tid; idx < LPB * NLINE; idx += LPB) {
            const int l = idx / NLINE;
            const int n = idx - l * NLINE;
            dst[idx] = lds[swz(l, n)];
        }
    } else {
        const int L = L0 + tid;
        const int o = L / I;
        const int i = L - o * I;
        float* dst = out + (size_t)o * NLINE * I + i;
        #pragma unroll 4
        for (int n = 0; n < NLINE; ++n)
            dst[(size_t)n * I] = lds[swz(tid, n)];
    }
}

extern "C" void kernel_launch(void* const* d_in, const int* in_sizes, int n_in,
                              void* d_out, int out_size, void* d_ws, size_t ws_size,
                              hipStream_t stream) {
    (void)in_sizes; (void)n_in; (void)d_ws; (void)ws_size; (void)out_size;
    const float* x = (const float*)d_in[0];
    float* out = (float*)d_out;

    // shape (2,3,160,160,160): 153600 lines per axis, 160*160*160 per (b,c)
    const int lines = 2 * 3 * 160 * 160;          // 153600, divisible by 64
    const dim3 grid(lines / LPB), block(LPB);

    // axis 2 (stride 160*160), then axis 3 (stride 160), then axis 4 (stride 1).
    // Passes 2 and 3 run in-place on d_out: each block reads exactly the lines
    // it writes (disjoint across blocks), so in-place is race-free.
    prefilter<160 * 160><<<grid, block, 0, stream>>>(x,   out);
    prefilter<160>      <<<grid, block, 0, stream>>>(out, out);
    prefilter<1>        <<<grid, block, 0, stream>>>(out, out);
}

// Round 2
// 115.936 us; speedup vs baseline: 2.1129x; 2.1129x over previous
//
#include <hip/hip_runtime.h>

// Cubic B-spline prefilter (Unser), periodic boundary, axes 2,3,4 of
// (2,3,160,160,160) fp32. One thread per line; the whole 160-element line
// lives in REGISTERS (fully unrolled sweeps, static indices). No LDS at all:
// VGPR file holds 512 lines/CU (2 waves/SIMD at <=256 VGPR) vs the LDS
// design's 256 lines/CU, and the dependent-FMA sweeps never touch memory.

#define NLINE 160
#define LPB   64

template <int I>  // stride between successive elements of a line
__global__ __launch_bounds__(LPB, 2)   // min 2 waves/EU -> cap at 256 VGPR
void prefilter(const float* __restrict__ in, float* __restrict__ out)
{
    const int L = blockIdx.x * LPB + threadIdx.x;   // line id (grid covers all)
    const float z = -0.26794919243112270647f;       // sqrt(3) - 2

    float v[NLINE];

    // ---- load line into registers ----
    if (I == 1) {
        // contiguous line: 40x float4 per thread (16B/lane; L1 absorbs the
        // 4x cache-line re-touch across lanes)
        const float4* src = reinterpret_cast<const float4*>(in + (size_t)L * NLINE);
        #pragma unroll
        for (int n = 0; n < NLINE / 4; ++n) {
            const float4 q = src[n];
            v[4*n+0] = q.x; v[4*n+1] = q.y; v[4*n+2] = q.z; v[4*n+3] = q.w;
        }
    } else {
        // strided line: consecutive lanes -> consecutive addresses (coalesced)
        const int o = L / I;
        const int i = L - o * I;
        const float* src = in + (size_t)o * (NLINE * (size_t)I) + i;
        #pragma unroll
        for (int n = 0; n < NLINE; ++n)
            v[n] = src[(size_t)n * I];
    }

    // ---- causal init (periodic): acc = sum_{k=1..N-1} z^(N-k) x[k] ----
    // (z^160 underflows to 0 in fp32 -> the 1/(1-z^N) factor is exactly 1,
    //  matching the fp32 JAX reference.)
    float acc = v[1];
    #pragma unroll
    for (int n = 2; n < NLINE; ++n)
        acc = fmaf(acc, z, v[n]);
    acc *= z;

    // ---- forward sweep: cp[n] = 6*x[n] + z*cp[n-1]; accumulate
    //      T = sum_{k=1..N-1} z^k cp[k-1] for the anticausal init ----
    float cp = 6.0f * (v[0] + acc);
    v[0] = cp;
    float T = 0.0f, zp = z;
    #pragma unroll
    for (int n = 1; n < NLINE; ++n) {
        const float cn = fmaf(z, cp, 6.0f * v[n]);
        T  = fmaf(zp, cp, T);
        zp *= z;                    // constant-folds under full unroll
        cp = cn;
        v[n] = cp;
    }

    // ---- anticausal init: cm[N-1] = -z * (cp[N-1] + T) ----
    float cm = -z * (cp + T);
    v[NLINE - 1] = cm;

    // ---- backward sweep: cm[n] = z * (cm[n+1] - cp[n]) ----
    #pragma unroll
    for (int n = NLINE - 2; n >= 0; --n) {
        cm = z * (cm - v[n]);
        v[n] = cm;
    }

    // ---- store line ----
    if (I == 1) {
        float4* dst = reinterpret_cast<float4*>(out + (size_t)L * NLINE);
        #pragma unroll
        for (int n = 0; n < NLINE / 4; ++n) {
            float4 q;
            q.x = v[4*n+0]; q.y = v[4*n+1]; q.z = v[4*n+2]; q.w = v[4*n+3];
            dst[n] = q;
        }
    } else {
        const int o = L / I;
        const int i = L - o * I;
        float* dst = out + (size_t)o * (NLINE * (size_t)I) + i;
        #pragma unroll
        for (int n = 0; n < NLINE; ++n)
            dst[(size_t)n * I] = v[n];
    }
}

extern "C" void kernel_launch(void* const* d_in, const int* in_sizes, int n_in,
                              void* d_out, int out_size, void* d_ws, size_t ws_size,
                              hipStream_t stream) {
    (void)in_sizes; (void)n_in; (void)d_ws; (void)ws_size; (void)out_size;
    const float* x = (const float*)d_in[0];
    float* out = (float*)d_out;

    const int lines = 2 * 3 * 160 * 160;          // 153600 lines per axis
    const dim3 grid(lines / LPB), block(LPB);

    // axis 2 (stride 160*160) -> axis 3 (stride 160) -> axis 4 (stride 1).
    // Each thread reads/writes only its own line -> in-place passes race-free.
    prefilter<160 * 160><<<grid, block, 0, stream>>>(x,   out);
    prefilter<160>      <<<grid, block, 0, stream>>>(out, out);
    prefilter<1>        <<<grid, block, 0, stream>>>(out, out);
}